// Round 3
// baseline (1801.487 us; speedup 1.0000x reference)
//
#include <hip/hip_runtime.h>

#define N_ROWS 100000
#define IN_F   8192
#define OUT_F  128
#define NNZ    2000000

#define BROWS  64                                  // rows per bucket
#define NB     ((N_ROWS + BROWS - 1) / BROWS)      // 1563 buckets
#define CAP    2048                                // mean fill 1280, sigma ~36

// ---------------------------------------------------------------------------
// transpose weight [OUT_F, IN_F] -> wT [IN_F, OUT_F]
// ---------------------------------------------------------------------------
__global__ void transpose_w(const float* __restrict__ w, float* __restrict__ wT) {
    __shared__ float tile[32][33];
    int x = blockIdx.x * 32 + threadIdx.x;
    int y = blockIdx.y * 32 + threadIdx.y;
    #pragma unroll
    for (int i = 0; i < 32; i += 8)
        tile[threadIdx.y + i][threadIdx.x] = w[(size_t)(y + i) * IN_F + x];
    __syncthreads();
    int tx = blockIdx.y * 32 + threadIdx.x;
    int ty = blockIdx.x * 32 + threadIdx.y;
    #pragma unroll
    for (int i = 0; i < 32; i += 8)
        wT[(size_t)(ty + i) * OUT_F + tx] = tile[threadIdx.x][threadIdx.y + i];
}

// ---------------------------------------------------------------------------
// zero bucket counters (every call)
// ---------------------------------------------------------------------------
__global__ void zero_cnt(int* __restrict__ cnt) {
    int i = blockIdx.x * blockDim.x + threadIdx.x;
    if (i < NB) cnt[i] = 0;
}

// ---------------------------------------------------------------------------
// pass A: bin nonzeros into 64-row buckets.
// record = ((r&63)<<13 | c, val). Frontier = NB lines ~100 KB, L2-resident
// -> full-line write utilization (vs 8x amplification of per-row scatter).
// ---------------------------------------------------------------------------
__global__ void bin_pass(const int* __restrict__ rows, const int* __restrict__ cols,
                         const float* __restrict__ vals, int* __restrict__ cnt,
                         int2* __restrict__ buckets) {
    int i = blockIdx.x * blockDim.x + threadIdx.x;
    if (i >= NNZ) return;
    int r = rows[i];
    int c = cols[i];
    int b = r >> 6;                                // r / BROWS
    int p = atomicAdd(&cnt[b], 1);
    if (p < CAP)                                   // never hit with this data; safety
        buckets[(size_t)b * CAP + p] =
            make_int2(((r & 63) << 13) | c, __float_as_int(vals[i]));
}

// ---------------------------------------------------------------------------
// pass B: one block per bucket. LDS acc[64][128] (32 KB), LDS-atomic f32
// accumulate (bank-conflict-free: lane owns cols {l, 64+l}), single
// coalesced store of acc+bias. Replaces scan + pair scatter + global reduce.
// ---------------------------------------------------------------------------
__global__ void __launch_bounds__(256) bucket_reduce(const int2* __restrict__ buckets,
                                                     const int* __restrict__ cnt,
                                                     const float* __restrict__ wT,
                                                     const float* __restrict__ bias,
                                                     float* __restrict__ out) {
    __shared__ float acc[BROWS * OUT_F];           // 32 KB
    __shared__ int2  stage[256];                   // 2 KB
    int b    = blockIdx.x;
    int t    = threadIdx.x;
    int lane = t & 63;
    int w    = t >> 6;

    #pragma unroll
    for (int i = t; i < BROWS * OUT_F; i += 256) acc[i] = 0.f;

    int n = cnt[b];
    if (n > CAP) n = CAP;
    const int2* bk = buckets + (size_t)b * CAP;

    for (int base = 0; base < n; base += 256) {
        int m = n - base;
        if (m > 256) m = 256;
        __syncthreads();                           // stage reuse + first-iter acc fence
        if (t < m) stage[t] = bk[base + t];
        __syncthreads();
        int lo = w * 64;
        int hi = lo + 64 < m ? lo + 64 : m;
        #pragma unroll 4
        for (int k = lo; k < hi; ++k) {
            int2 rec = stage[k];                   // broadcast LDS read
            int   r  = rec.x >> 13;
            int   c  = rec.x & 8191;
            float v  = __int_as_float(rec.y);
            const float* wrow = wT + (size_t)c * OUT_F;
            atomicAdd(&acc[r * OUT_F + lane],      v * wrow[lane]);       // ds_add_f32
            atomicAdd(&acc[r * OUT_F + 64 + lane], v * wrow[64 + lane]);
        }
    }
    __syncthreads();

    // epilogue: out = acc + bias, coalesced float4
    int row0 = b * BROWS;
    int vr = N_ROWS - row0;
    if (vr > BROWS) vr = BROWS;
    const float4* acc4  = (const float4*)acc;
    const float4* bias4 = (const float4*)bias;
    float4* out4 = (float4*)(out + (size_t)row0 * OUT_F);
    int total4 = vr * (OUT_F / 4);
    for (int i = t; i < total4; i += 256) {
        int c4 = i & 31;
        float4 a = acc4[i], bb = bias4[c4];
        a.x += bb.x; a.y += bb.y; a.z += bb.z; a.w += bb.w;
        out4[i] = a;
    }
}

// ---------------------------------------------------------------------------
// fallback (ws too small): bias init + atomic scatter — correct but slow
// ---------------------------------------------------------------------------
__global__ void init_out(float4* __restrict__ out4, const float4* __restrict__ bias4) {
    int i = blockIdx.x * blockDim.x + threadIdx.x;
    if (i >= N_ROWS * OUT_F / 4) return;
    out4[i] = bias4[i & 31];
}

__global__ void scatter_noT(const int* __restrict__ rows, const int* __restrict__ cols,
                            const float* __restrict__ vals, const float* __restrict__ w,
                            float* __restrict__ out) {
    int t    = blockIdx.x * blockDim.x + threadIdx.x;
    int nz   = t >> 5;
    int lane = t & 31;
    if (nz >= NNZ) return;
    int   r = rows[nz];
    int   c = cols[nz];
    float v = vals[nz];
    float* o = out + (size_t)r * OUT_F + lane * 4;
    #pragma unroll
    for (int k = 0; k < 4; ++k) {
        float wv = w[(size_t)(lane * 4 + k) * IN_F + c];
        atomicAdd(o + k, v * wv);
    }
}

extern "C" void kernel_launch(void* const* d_in, const int* in_sizes, int n_in,
                              void* d_out, int out_size, void* d_ws, size_t ws_size,
                              hipStream_t stream) {
    const int*   rows   = (const int*)d_in[0];
    const int*   cols   = (const int*)d_in[1];
    const float* vals   = (const float*)d_in[2];
    const float* weight = (const float*)d_in[3];
    const float* bias   = (const float*)d_in[4];
    float* out = (float*)d_out;

    // workspace layout
    char* ws = (char*)d_ws;
    size_t off = 0;
    float* wT      = (float*)(ws + off); off += (size_t)IN_F * OUT_F * sizeof(float); // 4 MB
    int*   cnt     = (int*)(ws + off);   off += ((size_t)NB * 4 + 7) & ~(size_t)7;
    int2*  buckets = (int2*)(ws + off);  off += (size_t)NB * CAP * 8;                 // 25.6 MB

    if (ws_size >= off) {
        {
            dim3 bdim(32, 8), g(IN_F / 32, OUT_F / 32);
            transpose_w<<<g, bdim, 0, stream>>>(weight, wT);
        }
        zero_cnt<<<(NB + 255) / 256, 256, 0, stream>>>(cnt);
        bin_pass<<<(NNZ + 255) / 256, 256, 0, stream>>>(rows, cols, vals, cnt, buckets);
        bucket_reduce<<<NB, 256, 0, stream>>>(buckets, cnt, wT, bias, out);
    } else {
        int n4 = N_ROWS * OUT_F / 4;
        init_out<<<(n4 + 255) / 256, 256, 0, stream>>>((float4*)out, (const float4*)bias);
        long long total = (long long)NNZ * 32;
        scatter_noT<<<(int)((total + 255) / 256), 256, 0, stream>>>(rows, cols, vals, weight, out);
    }
}

// Round 4
// 433.195 us; speedup vs baseline: 4.1586x; 4.1586x over previous
//
#include <hip/hip_runtime.h>

#define N_ROWS 100000
#define IN_F   8192
#define OUT_F  128
#define NNZ    2000000

#define BROWS  64                                  // rows per bucket
#define NB     ((N_ROWS + BROWS - 1) / BROWS)      // 1563 buckets
#define CAP    2048                                // mean fill 1280, max ~1450

// ---------------------------------------------------------------------------
// transpose weight [OUT_F, IN_F] -> wT [IN_F, OUT_F]
// ---------------------------------------------------------------------------
__global__ void transpose_w(const float* __restrict__ w, float* __restrict__ wT) {
    __shared__ float tile[32][33];
    int x = blockIdx.x * 32 + threadIdx.x;
    int y = blockIdx.y * 32 + threadIdx.y;
    #pragma unroll
    for (int i = 0; i < 32; i += 8)
        tile[threadIdx.y + i][threadIdx.x] = w[(size_t)(y + i) * IN_F + x];
    __syncthreads();
    int tx = blockIdx.y * 32 + threadIdx.x;
    int ty = blockIdx.x * 32 + threadIdx.y;
    #pragma unroll
    for (int i = 0; i < 32; i += 8)
        wT[(size_t)(ty + i) * OUT_F + tx] = tile[threadIdx.x][threadIdx.y + i];
}

__global__ void zero_cnt(int* __restrict__ cnt) {
    int i = blockIdx.x * blockDim.x + threadIdx.x;
    if (i < NB) cnt[i] = 0;
}

// ---------------------------------------------------------------------------
// pass A: bin nonzeros into 64-row buckets. Frontier = 1563 lines (~100 KB,
// L2-resident) -> no partial-line write amplification.
// record = ((r&63)<<13 | c, val)
// ---------------------------------------------------------------------------
__global__ void bin_pass(const int* __restrict__ rows, const int* __restrict__ cols,
                         const float* __restrict__ vals, int* __restrict__ cnt,
                         int2* __restrict__ buckets) {
    int i = blockIdx.x * blockDim.x + threadIdx.x;
    if (i >= NNZ) return;
    int r = rows[i];
    int c = cols[i];
    int b = r >> 6;
    int p = atomicAdd(&cnt[b], 1);
    if (p < CAP)                                   // safety; never hit with this data
        buckets[(size_t)b * CAP + p] =
            make_int2(((r & 63) << 13) | c, __float_as_int(vals[i]));
}

// ---------------------------------------------------------------------------
// pass B: in-place counting sort by row within each bucket (one block/bucket).
// Stage all records in LDS, per-wave hist over 64 rows, wave-0 shfl scan,
// scatter back row-sorted; emit per-row [start,end) into global arrays.
// ---------------------------------------------------------------------------
__global__ void __launch_bounds__(256) bucket_sort(int2* __restrict__ buckets,
                                                   const int* __restrict__ cnt,
                                                   int* __restrict__ starts,
                                                   int* __restrict__ ends) {
    __shared__ int2 stage[CAP];                    // 16 KB
    __shared__ int  hist[4][BROWS];                // per-wave hist (1 KB)
    __shared__ int  offs[BROWS];
    __shared__ int  cur[BROWS];
    int b = blockIdx.x, t = threadIdx.x;
    int w = t >> 6, lane = t & 63;
    int n = cnt[b]; if (n > CAP) n = CAP;
    int2* bk = buckets + (size_t)b * CAP;

    if (t < BROWS) { hist[0][t] = 0; hist[1][t] = 0; hist[2][t] = 0; hist[3][t] = 0; }
    __syncthreads();

    for (int i = t; i < n; i += 256) {
        int2 rec = bk[i];
        stage[i] = rec;
        atomicAdd(&hist[w][rec.x >> 13], 1);
    }
    __syncthreads();

    if (t < BROWS) {
        int c = hist[0][t] + hist[1][t] + hist[2][t] + hist[3][t];
        int s = c;                                 // inclusive scan over 64 lanes
        #pragma unroll
        for (int d = 1; d < 64; d <<= 1) {
            int u = __shfl_up(s, d, 64);
            if (lane >= d) s += u;
        }
        int start = s - c;                         // exclusive
        offs[t] = start;
        cur[t]  = 0;
        int row = b * BROWS + t;
        if (row < N_ROWS) {
            starts[row] = b * CAP + start;
            ends[row]   = b * CAP + start + c;
        }
    }
    __syncthreads();

    for (int i = t; i < n; i += 256) {
        int2 rec = stage[i];
        int r = rec.x >> 13;
        int p = atomicAdd(&cur[r], 1);
        bk[offs[r] + p] = rec;                     // random within 16 KB: L2 absorbs
    }
}

// ---------------------------------------------------------------------------
// pass C: one wave per row, register-accumulated segment reduction.
// lane l owns output cols {2l, 2l+1}. (Round-2 kernel, measured good.)
// ---------------------------------------------------------------------------
__global__ void __launch_bounds__(256) reduce_rows(const int2* __restrict__ pairs,
                                                   const float* __restrict__ wT,
                                                   const int* __restrict__ starts,
                                                   const int* __restrict__ ends,
                                                   const float* __restrict__ bias,
                                                   float* __restrict__ out) {
    int wid  = (blockIdx.x * blockDim.x + threadIdx.x) >> 6;   // row
    int lane = threadIdx.x & 63;
    if (wid >= N_ROWS) return;
    int p   = starts[wid];
    int end = ends[wid];
    float2 acc = *reinterpret_cast<const float2*>(bias + 2 * lane);
    for (; p + 2 <= end; p += 2) {
        int2 pa = pairs[p];
        int2 pb = pairs[p + 1];
        float va = __int_as_float(pa.y);
        float vb = __int_as_float(pb.y);
        float2 wa = *reinterpret_cast<const float2*>(wT + (size_t)(pa.x & 8191) * OUT_F + 2 * lane);
        float2 wb = *reinterpret_cast<const float2*>(wT + (size_t)(pb.x & 8191) * OUT_F + 2 * lane);
        acc.x += va * wa.x;
        acc.y += va * wa.y;
        acc.x += vb * wb.x;
        acc.y += vb * wb.y;
    }
    if (p < end) {
        int2 pa = pairs[p];
        float va = __int_as_float(pa.y);
        float2 wa = *reinterpret_cast<const float2*>(wT + (size_t)(pa.x & 8191) * OUT_F + 2 * lane);
        acc.x += va * wa.x;
        acc.y += va * wa.y;
    }
    *reinterpret_cast<float2*>(out + (size_t)wid * OUT_F + 2 * lane) = acc;
}

// ---------------------------------------------------------------------------
// fallback (ws too small): bias init + atomic scatter — correct but slow
// ---------------------------------------------------------------------------
__global__ void init_out(float4* __restrict__ out4, const float4* __restrict__ bias4) {
    int i = blockIdx.x * blockDim.x + threadIdx.x;
    if (i >= N_ROWS * OUT_F / 4) return;
    out4[i] = bias4[i & 31];
}

__global__ void scatter_noT(const int* __restrict__ rows, const int* __restrict__ cols,
                            const float* __restrict__ vals, const float* __restrict__ w,
                            float* __restrict__ out) {
    int t    = blockIdx.x * blockDim.x + threadIdx.x;
    int nz   = t >> 5;
    int lane = t & 31;
    if (nz >= NNZ) return;
    int   r = rows[nz];
    int   c = cols[nz];
    float v = vals[nz];
    float* o = out + (size_t)r * OUT_F + lane * 4;
    #pragma unroll
    for (int k = 0; k < 4; ++k) {
        float wv = w[(size_t)(lane * 4 + k) * IN_F + c];
        atomicAdd(o + k, v * wv);
    }
}

extern "C" void kernel_launch(void* const* d_in, const int* in_sizes, int n_in,
                              void* d_out, int out_size, void* d_ws, size_t ws_size,
                              hipStream_t stream) {
    const int*   rows   = (const int*)d_in[0];
    const int*   cols   = (const int*)d_in[1];
    const float* vals   = (const float*)d_in[2];
    const float* weight = (const float*)d_in[3];
    const float* bias   = (const float*)d_in[4];
    float* out = (float*)d_out;

    // workspace layout (~30.5 MB)
    char* ws = (char*)d_ws;
    size_t off = 0;
    float* wT      = (float*)(ws + off); off += (size_t)IN_F * OUT_F * sizeof(float); // 4 MB
    int*   cnt     = (int*)(ws + off);   off += ((size_t)NB * 4 + 7) & ~(size_t)7;
    int*   starts  = (int*)(ws + off);   off += (size_t)N_ROWS * 4;                   // 400 KB
    int*   ends    = (int*)(ws + off);   off += (size_t)N_ROWS * 4;                   // 400 KB
    off = (off + 7) & ~(size_t)7;
    int2*  buckets = (int2*)(ws + off);  off += (size_t)NB * CAP * 8;                 // 25.6 MB

    if (ws_size >= off) {
        {
            dim3 bdim(32, 8), g(IN_F / 32, OUT_F / 32);
            transpose_w<<<g, bdim, 0, stream>>>(weight, wT);
        }
        zero_cnt<<<(NB + 255) / 256, 256, 0, stream>>>(cnt);
        bin_pass<<<(NNZ + 255) / 256, 256, 0, stream>>>(rows, cols, vals, cnt, buckets);
        bucket_sort<<<NB, 256, 0, stream>>>(buckets, cnt, starts, ends);
        {
            int waves_per_block = 256 / 64;
            int blocks = (N_ROWS + waves_per_block - 1) / waves_per_block;
            reduce_rows<<<blocks, 256, 0, stream>>>(buckets, wT, starts, ends, bias, out);
        }
    } else {
        int n4 = N_ROWS * OUT_F / 4;
        init_out<<<(n4 + 255) / 256, 256, 0, stream>>>((float4*)out, (const float4*)bias);
        long long total = (long long)NNZ * 32;
        scatter_noT<<<(int)((total + 255) / 256), 256, 0, stream>>>(rows, cols, vals, weight, out);
    }
}

// Round 5
// 384.324 us; speedup vs baseline: 4.6874x; 1.1272x over previous
//
#include <hip/hip_runtime.h>

#define N_ROWS 100000
#define IN_F   8192
#define OUT_F  128
#define NNZ    2000000

#define NREG   8                                    // regions = XCDs (blockIdx & 7)
#define FLATN  (NREG * N_ROWS)                      // 800000 (region-major counters)
#define SCAN_B 1024
#define NBLK2  ((FLATN + SCAN_B - 1) / SCAN_B)      // 782
#define NPAD2  (NBLK2 * SCAN_B)                     // 800768

// ---------------------------------------------------------------------------
// transpose weight [OUT_F, IN_F] -> wT [IN_F, OUT_F]
// ---------------------------------------------------------------------------
__global__ void transpose_w(const float* __restrict__ w, float* __restrict__ wT) {
    __shared__ float tile[32][33];
    int x = blockIdx.x * 32 + threadIdx.x;
    int y = blockIdx.y * 32 + threadIdx.y;
    #pragma unroll
    for (int i = 0; i < 32; i += 8)
        tile[threadIdx.y + i][threadIdx.x] = w[(size_t)(y + i) * IN_F + x];
    __syncthreads();
    int tx = blockIdx.y * 32 + threadIdx.x;
    int ty = blockIdx.x * 32 + threadIdx.y;
    #pragma unroll
    for (int i = 0; i < 32; i += 8)
        wT[(size_t)(ty + i) * OUT_F + tx] = tile[threadIdx.x][threadIdx.y + i];
}

// ---------------------------------------------------------------------------
// zero counts[NPAD2] + blockSums[SCAN_B] (every call)
// ---------------------------------------------------------------------------
__global__ void zero_counts(int* __restrict__ counts, int* __restrict__ blockSums) {
    int i = blockIdx.x * blockDim.x + threadIdx.x;
    if (i < NPAD2) counts[i] = 0;
    if (i < SCAN_B) blockSums[i] = 0;
}

// ---------------------------------------------------------------------------
// histogram into region-major counters: region j = blockIdx & 7 (== XCD under
// default round-robin dispatch) -> counter lines are XCD-local, no ping-pong.
// ---------------------------------------------------------------------------
__global__ void hist8(const int* __restrict__ rows, int* __restrict__ counts) {
    int i = blockIdx.x * blockDim.x + threadIdx.x;
    if (i >= NNZ) return;
    int j = blockIdx.x & 7;
    atomicAdd(&counts[j * N_ROWS + rows[i]], 1);
}

// ---------------------------------------------------------------------------
// per-block exclusive scan, IN PLACE on counts; emits block totals
// ---------------------------------------------------------------------------
__global__ void scan_blocks(int* __restrict__ counts, int* __restrict__ blockSums) {
    __shared__ int sh[SCAN_B];
    int tid = threadIdx.x;
    int gid = blockIdx.x * SCAN_B + tid;
    int v = counts[gid];
    sh[tid] = v;
    __syncthreads();
    for (int off = 1; off < SCAN_B; off <<= 1) {
        int t = (tid >= off) ? sh[tid - off] : 0;
        __syncthreads();
        sh[tid] += t;
        __syncthreads();
    }
    counts[gid] = sh[tid] - v;                     // exclusive within block
    if (tid == SCAN_B - 1) blockSums[blockIdx.x] = sh[tid];
}

// ---------------------------------------------------------------------------
// single-block exclusive scan of blockSums (NBLK2 <= SCAN_B, padding zeroed)
// ---------------------------------------------------------------------------
__global__ void scan_sums(int* __restrict__ blockSums) {
    __shared__ int sh[SCAN_B];
    int tid = threadIdx.x;
    int v = blockSums[tid];
    sh[tid] = v;
    __syncthreads();
    for (int off = 1; off < SCAN_B; off <<= 1) {
        int t = (tid >= off) ? sh[tid - off] : 0;
        __syncthreads();
        sh[tid] += t;
        __syncthreads();
    }
    blockSums[tid] = sh[tid] - v;
}

// ---------------------------------------------------------------------------
// offsets[gid] = scan value (kept for reduce); counts[gid] := same (cursors)
// ---------------------------------------------------------------------------
__global__ void finalize_offsets(int* __restrict__ counts, const int* __restrict__ blockSums,
                                 int* __restrict__ offsets) {
    int gid = blockIdx.x * SCAN_B + threadIdx.x;
    int off = counts[gid] + blockSums[gid >> 10];
    offsets[gid] = off;
    counts[gid] = off;                             // reuse as cursors
}

// ---------------------------------------------------------------------------
// scatter (col,val) into row-sorted order within this block's region.
// Region pairs-span + cursor lines touched by ONE XCD only -> lines fill,
// single writeback (kills the 64B-per-record cross-XCD flush).
// ---------------------------------------------------------------------------
__global__ void scatter8(const int* __restrict__ rows, const int* __restrict__ cols,
                         const float* __restrict__ vals, int* __restrict__ cursors,
                         int2* __restrict__ pairs) {
    int i = blockIdx.x * blockDim.x + threadIdx.x;
    if (i >= NNZ) return;
    int j = blockIdx.x & 7;                        // MUST match hist8 (same grid shape)
    int r = rows[i];
    int p = atomicAdd(&cursors[j * N_ROWS + r], 1);
    pairs[p] = make_int2(cols[i], __float_as_int(vals[i]));
}

// ---------------------------------------------------------------------------
// one wave per row: walk the row's 8 region-segments, register accumulate,
// single store. Segment (j,r) = [offs[j*N+r], offs[j*N+r+1]) — contiguous scan.
// ---------------------------------------------------------------------------
__global__ void __launch_bounds__(256) reduce_rows(const int2* __restrict__ pairs,
                                                   const float* __restrict__ wT,
                                                   const int* __restrict__ offsets,
                                                   const float* __restrict__ bias,
                                                   float* __restrict__ out) {
    int wid  = (blockIdx.x * blockDim.x + threadIdx.x) >> 6;   // row
    int lane = threadIdx.x & 63;
    if (wid >= N_ROWS) return;
    float2 acc = *reinterpret_cast<const float2*>(bias + 2 * lane);
    #pragma unroll
    for (int j = 0; j < NREG; ++j) {
        int f = j * N_ROWS + wid;
        int p = offsets[f];
        int e = offsets[f + 1];                    // valid: contiguous region-major scan
        for (; p + 2 <= e; p += 2) {
            int2 pa = pairs[p];
            int2 pb = pairs[p + 1];
            float va = __int_as_float(pa.y);
            float vb = __int_as_float(pb.y);
            float2 wa = *reinterpret_cast<const float2*>(wT + (size_t)pa.x * OUT_F + 2 * lane);
            float2 wb = *reinterpret_cast<const float2*>(wT + (size_t)pb.x * OUT_F + 2 * lane);
            acc.x += va * wa.x;
            acc.y += va * wa.y;
            acc.x += vb * wb.x;
            acc.y += vb * wb.y;
        }
        if (p < e) {
            int2 pa = pairs[p];
            float va = __int_as_float(pa.y);
            float2 wa = *reinterpret_cast<const float2*>(wT + (size_t)pa.x * OUT_F + 2 * lane);
            acc.x += va * wa.x;
            acc.y += va * wa.y;
        }
    }
    __builtin_nontemporal_store(acc.x, out + (size_t)wid * OUT_F + 2 * lane);
    __builtin_nontemporal_store(acc.y, out + (size_t)wid * OUT_F + 2 * lane + 1);
}

// ---------------------------------------------------------------------------
// fallback (ws too small): bias init + atomic scatter — correct but slow
// ---------------------------------------------------------------------------
__global__ void init_out(float4* __restrict__ out4, const float4* __restrict__ bias4) {
    int i = blockIdx.x * blockDim.x + threadIdx.x;
    if (i >= N_ROWS * OUT_F / 4) return;
    out4[i] = bias4[i & 31];
}

__global__ void scatter_noT(const int* __restrict__ rows, const int* __restrict__ cols,
                            const float* __restrict__ vals, const float* __restrict__ w,
                            float* __restrict__ out) {
    int t    = blockIdx.x * blockDim.x + threadIdx.x;
    int nz   = t >> 5;
    int lane = t & 31;
    if (nz >= NNZ) return;
    int   r = rows[nz];
    int   c = cols[nz];
    float v = vals[nz];
    float* o = out + (size_t)r * OUT_F + lane * 4;
    #pragma unroll
    for (int k = 0; k < 4; ++k) {
        float wv = w[(size_t)(lane * 4 + k) * IN_F + c];
        atomicAdd(o + k, v * wv);
    }
}

extern "C" void kernel_launch(void* const* d_in, const int* in_sizes, int n_in,
                              void* d_out, int out_size, void* d_ws, size_t ws_size,
                              hipStream_t stream) {
    const int*   rows   = (const int*)d_in[0];
    const int*   cols   = (const int*)d_in[1];
    const float* vals   = (const float*)d_in[2];
    const float* weight = (const float*)d_in[3];
    const float* bias   = (const float*)d_in[4];
    float* out = (float*)d_out;

    // workspace layout (~26.6 MB)
    char* ws = (char*)d_ws;
    size_t off = 0;
    float* wT       = (float*)(ws + off); off += (size_t)IN_F * OUT_F * sizeof(float); // 4 MB
    int*   counts   = (int*)(ws + off);   off += (size_t)NPAD2 * 4;                    // 3.2 MB (-> cursors)
    int*   offsets  = (int*)(ws + off);   off += (size_t)NPAD2 * 4;                    // 3.2 MB
    int*   blockSums= (int*)(ws + off);   off += (size_t)SCAN_B * 4;
    off = (off + 7) & ~(size_t)7;
    int2*  pairs    = (int2*)(ws + off);  off += (size_t)NNZ * 8;                      // 16 MB

    if (ws_size >= off) {
        {
            dim3 bdim(32, 8), g(IN_F / 32, OUT_F / 32);
            transpose_w<<<g, bdim, 0, stream>>>(weight, wT);
        }
        zero_counts<<<NBLK2, SCAN_B, 0, stream>>>(counts, blockSums);
        {
            int nb = (NNZ + 255) / 256;
            hist8<<<nb, 256, 0, stream>>>(rows, counts);
            scan_blocks<<<NBLK2, SCAN_B, 0, stream>>>(counts, blockSums);
            scan_sums<<<1, SCAN_B, 0, stream>>>(blockSums);
            finalize_offsets<<<NBLK2, SCAN_B, 0, stream>>>(counts, blockSums, offsets);
            scatter8<<<nb, 256, 0, stream>>>(rows, cols, vals, counts, pairs);
        }
        {
            int blocks = (N_ROWS + 3) / 4;         // 4 waves (rows) per 256-thread block
            reduce_rows<<<blocks, 256, 0, stream>>>(pairs, wT, offsets, bias, out);
        }
    } else {
        int n4 = N_ROWS * OUT_F / 4;
        init_out<<<(n4 + 255) / 256, 256, 0, stream>>>((float4*)out, (const float4*)bias);
        long long total = (long long)NNZ * 32;
        scatter_noT<<<(int)((total + 255) / 256), 256, 0, stream>>>(rows, cols, vals, weight, out);
    }
}